// Round 1
// baseline (1080.190 us; speedup 1.0000x reference)
//
#include <hip/hip_runtime.h>
#include <stdint.h>

// ---------------------------------------------------------------------------
// SSL_34857954574989: dense SSM with spectral-norm-scaled K.
// Key identity: with w = S x, the S/Sinv conjugation cancels:
//   w_{t+1} = K11n w_t + gamma*K12n u_t   (K11n = 2x2 block-diag rotations)
//   y_t     = K21n w_t + gamma*K22n u_t
// So: GEMM1 (Bu = u@K12^T), elementwise chunked scan, GEMM2 ([pre|u]@[C|D]^T).
// sigma = ||K_raw||_2 via m=48 Lanczos on K^T K (96 small matvec kernels)
// + 64-way multisection Sturm bisection on the tridiagonal.
// ---------------------------------------------------------------------------

#define LM 48            // Lanczos steps
#define CHUNK 128        // scan chunk length
#define WARM 24          // scan warm-up steps (|lambda|^24 ~ 1e-42)

typedef float f32x4 __attribute__((ext_vector_type(4)));
typedef __bf16 bf16x8 __attribute__((ext_vector_type(8)));
typedef unsigned int u32;
typedef unsigned short u16;

static __device__ __forceinline__ u16 f2bf(float f){
  u32 u = __float_as_uint(f);
  u32 r = (u + 0x7fffu + ((u >> 16) & 1u)) >> 16;
  return (u16)r;
}

// ---------------------------------------------------------------- build K_raw
__global__ __launch_bounds__(256) void build_K(const float* rho_raw, const float* theta,
    const float* K12, const float* K21, const float* K22, float* K, float* KT){
  int idx = blockIdx.x * 256 + threadIdx.x;      // 0 .. 1024*1024-1
  int i = idx >> 10, j = idx & 1023;
  float v;
  if (i < 512){
    if (j < 512){
      v = 0.f;
      if ((i >> 1) == (j >> 1)){
        int p = i >> 1;
        float rho = (1.f / (1.f + expf(-rho_raw[p]))) * 0.999f;
        float c = cosf(theta[p]), s = sinf(theta[p]);
        v = ((i & 1) == 0) ? (((j & 1) == 0) ? rho * c : -rho * s)
                           : (((j & 1) == 0) ? rho * s :  rho * c);
      }
    } else v = K12[i * 512 + (j - 512)];
  } else {
    if (j < 512) v = K21[(i - 512) * 512 + j];
    else         v = K22[(i - 512) * 512 + (j - 512)];
  }
  K[idx] = v;
  KT[j * 1024 + i] = v;
}

// ---------------------------------------------------------------- Lanczos init
__global__ __launch_bounds__(256) void init_scalars(double* alpha, double* beta2){
  int t = threadIdx.x;
  if (t < LM) alpha[t] = 0.0;
  if (t < LM + 1) beta2[t] = 0.0;
}

__global__ __launch_bounds__(256) void init_v0(float* V0, double* beta2){
  int i = blockIdx.x * 256 + threadIdx.x;        // 4 blocks -> 1024
  float v = sinf(0.613f * (float)i + 0.271f) + 0.3f * sinf(0.0247f * (float)i + 1.3f);
  V0[i] = v;
  float sq = v * v;
  #pragma unroll
  for (int off = 32; off; off >>= 1) sq += __shfl_down(sq, off);
  __shared__ float red[4];
  if ((threadIdx.x & 63) == 0) red[threadIdx.x >> 6] = sq;
  __syncthreads();
  if (threadIdx.x == 0)
    atomicAdd(beta2, (double)(red[0] + red[1] + red[2] + red[3]));
}

// y = K * (vraw / sqrt(b2)), alpha += ||y||^2.  64 blocks x 256.
__global__ __launch_bounds__(256) void lanczos_av(const float* M, const float* vraw,
    const double* b2ptr, float* y, double* accum){
  __shared__ float vl[1024];
  __shared__ float red[4];
  double b2 = *b2ptr;
  float s = (b2 > 1e-280) ? (float)(1.0 / sqrt(b2)) : 0.f;
  for (int i = threadIdx.x; i < 1024; i += 256) vl[i] = vraw[i] * s;
  __syncthreads();
  int wave = threadIdx.x >> 6, lane = threadIdx.x & 63;
  float sq = 0.f;
  for (int rr = 0; rr < 4; ++rr){
    int row = blockIdx.x * 16 + wave * 4 + rr;
    const float* kr = M + (size_t)row * 1024;
    float p = 0.f;
    #pragma unroll
    for (int i2 = 0; i2 < 16; ++i2) p += kr[lane + 64 * i2] * vl[lane + 64 * i2];
    #pragma unroll
    for (int off = 32; off; off >>= 1) p += __shfl_down(p, off);
    if (lane == 0){ y[row] = p; sq += p * p; }
  }
  if (lane == 0) red[wave] = sq;
  __syncthreads();
  if (threadIdx.x == 0)
    atomicAdd(accum, (double)(red[0] + red[1] + red[2] + red[3]));
}

// z = K^T y ; w = z - alpha*v_j - beta_{j-1}*v_{j-1} ; beta2out += ||w||^2
__global__ __launch_bounds__(256) void lanczos_atw(const float* MT, const float* y,
    const float* vraw_j, const double* b2_j, const float* vraw_prev, const double* b2_jm1,
    const double* alpha_j, float* wout, double* accum, int j){
  __shared__ float yl[1024];
  __shared__ float red[4];
  for (int i = threadIdx.x; i < 1024; i += 256) yl[i] = y[i];
  __syncthreads();
  double b2 = *b2_j;
  float sj = (b2 > 1e-280) ? (float)(1.0 / sqrt(b2)) : 0.f;
  float betap = (float)sqrt(b2 > 0.0 ? b2 : 0.0);   // beta_{j-1} (valid for j>0)
  float alphaf = (float)(*alpha_j);
  float sp = 0.f;
  if (j > 0){
    double b2p = *b2_jm1;
    sp = (b2p > 1e-280) ? (float)(1.0 / sqrt(b2p)) : 0.f;
  }
  int wave = threadIdx.x >> 6, lane = threadIdx.x & 63;
  float sq = 0.f;
  for (int rr = 0; rr < 4; ++rr){
    int row = blockIdx.x * 16 + wave * 4 + rr;
    const float* kr = MT + (size_t)row * 1024;
    float p = 0.f;
    #pragma unroll
    for (int i2 = 0; i2 < 16; ++i2) p += kr[lane + 64 * i2] * yl[lane + 64 * i2];
    #pragma unroll
    for (int off = 32; off; off >>= 1) p += __shfl_down(p, off);
    if (lane == 0){
      float w = p - alphaf * (vraw_j[row] * sj);
      if (j > 0) w -= betap * (vraw_prev[row] * sp);
      wout[row] = w; sq += w * w;
    }
  }
  if (lane == 0) red[wave] = sq;
  __syncthreads();
  if (threadIdx.x == 0)
    atomicAdd(accum, (double)(red[0] + red[1] + red[2] + red[3]));
}

// ------------------------------------------------- finalize: sigma + scan coef
__global__ __launch_bounds__(256) void finalize_sigma(const double* alpha, const double* beta2,
    const float* rho_raw, const float* theta, const float* log_gamma,
    float* scal, float2* coef){
  __shared__ double sa[LM], sb2[LM + 1];
  __shared__ float sh_inv;
  int t = threadIdx.x;
  if (t < LM) sa[t] = alpha[t];
  if (t < LM + 1) sb2[t] = beta2[t];
  __syncthreads();
  if (t < 64){
    int lane = t;
    double lo = sa[0], hi = sa[0], bmax = 0.0;
    for (int i = 0; i < LM; ++i){
      if (sa[i] > lo) lo = sa[i];
      double bl = (i > 0) ? sqrt(fmax(sb2[i], 0.0)) : 0.0;
      double br = (i < LM - 1) ? sqrt(fmax(sb2[i + 1], 0.0)) : 0.0;
      double g = sa[i] + bl + br;
      if (g > hi) hi = g;
      if (i < LM - 1 && sb2[i + 1] > bmax) bmax = sb2[i + 1];
    }
    hi = hi + 1e-6 * fabs(hi) + 1e-20;
    lo = lo - 1e-6 * fabs(lo) - 1e-20;
    double pivmin = 1e-30 * bmax + 1e-300;
    for (int round = 0; round < 6; ++round){
      double x = lo + (hi - lo) * ((double)(lane + 1) / 65.0);
      double d = sa[0] - x; int cnt = (d < 0.0);
      for (int i = 1; i < LM; ++i){
        if (fabs(d) < pivmin) d = -pivmin;
        d = (sa[i] - x) - sb2[i] / d;
        cnt += (d < 0.0);
      }
      unsigned long long mk = __ballot(cnt >= LM);
      int bpos = (mk == 0ULL) ? 64 : (__ffsll((unsigned long long)mk) - 1);
      double xlo = __shfl(x, (bpos == 0) ? 0 : bpos - 1);
      double xhi = __shfl(x, (bpos == 64) ? 63 : bpos);
      double nlo = (bpos == 0) ? lo : xlo;
      double nhi = (bpos == 64) ? hi : xhi;
      lo = nlo; hi = nhi;
    }
    if (lane == 0){
      double lam = 0.5 * (lo + hi);
      double sig = (lam > 0.0) ? sqrt(lam) : 0.0;
      if (sig < 1e-5) sig = 1e-5;
      double spp = sig + 0.002;
      float inv = (float)(1.0 / spp);
      float g = expf(log_gamma[0]);
      scal[0] = inv; scal[1] = g; scal[2] = g * inv;
      sh_inv = inv;
    }
  }
  __syncthreads();
  float inv = sh_inv;
  float rho = (1.f / (1.f + expf(-rho_raw[t]))) * 0.999f;
  float c = cosf(theta[t]), s = sinf(theta[t]);
  coef[t] = make_float2(rho * c * inv, rho * s * inv);
}

// ------------------------------------------------------------- converts / prep
__global__ __launch_bounds__(256) void conv_u(const float4* u4, u16* X){
  long g = (long)blockIdx.x * 256 + threadIdx.x;     // 8388608 total
  float4 v = u4[g];
  int h4 = (int)(g & 127);
  long row = g >> 7;
  u16* dst = X + row * 1024 + 512 + h4 * 4;
  u32 lo = (u32)f2bf(v.x) | ((u32)f2bf(v.y) << 16);
  u32 hi = (u32)f2bf(v.z) | ((u32)f2bf(v.w) << 16);
  *((uint2*)dst) = make_uint2(lo, hi);
}

__global__ __launch_bounds__(256) void conv_w12(const float4* src, u16* dst){
  long g = (long)blockIdx.x * 256 + threadIdx.x;     // 65536 total
  float4 v = src[g];
  u32 lo = (u32)f2bf(v.x) | ((u32)f2bf(v.y) << 16);
  u32 hi = (u32)f2bf(v.z) | ((u32)f2bf(v.w) << 16);
  ((uint2*)dst)[g] = make_uint2(lo, hi);
}

__global__ __launch_bounds__(256) void build_wcat(const float* K21, const float* K22,
    const float* scal, u16* W){
  int idx = blockIdx.x * 256 + threadIdx.x;          // 524288 total
  int o = idx >> 10, c = idx & 1023;
  float inv = scal[0], gi = scal[2];
  float v = (c < 512) ? K21[o * 512 + c] * inv : K22[o * 512 + (c - 512)] * gi;
  W[idx] = f2bf(v);
}

// w0[b][n] = sum_m S[n][m] * state[b][m]
__global__ __launch_bounds__(256) void w0_matvec(const float* S, const float* state, float* w0){
  int idx = blockIdx.x * 256 + threadIdx.x;          // 8192 total
  int b = idx >> 9, n = idx & 511;
  const float* sr = S + n * 512;
  const float* st = state + b * 512;
  float acc = 0.f;
  for (int m2 = 0; m2 < 512; ++m2) acc += sr[m2] * st[m2];
  w0[idx] = acc;
}

// ------------------------------------------------------------------- the scan
__global__ __launch_bounds__(256) void scan_kernel(const float* Bu, const float2* coef,
    const float* w0, const float* scal, u16* X){
  int b = blockIdx.x >> 5;           // 16 batches
  int c = blockIdx.x & 31;           // 32 chunks of 128
  int p = threadIdx.x;               // 256 pairs
  float2 ab = coef[p];
  float gi = scal[2];
  int t0 = c * CHUNK;
  float wx, wy; int t;
  if (c == 0){ wx = w0[b * 512 + 2 * p]; wy = w0[b * 512 + 2 * p + 1]; t = 0; }
  else { wx = 0.f; wy = 0.f; t = t0 - WARM; }
  const float* bub = Bu + (size_t)b * 4096 * 512;
  u16* xb = X + (size_t)b * 4096 * 1024;
  for (; t < t0; ++t){
    float2 bu = *(const float2*)(bub + (size_t)t * 512 + 2 * p);
    float nx = ab.x * wx - ab.y * wy + gi * bu.x;
    float ny = ab.y * wx + ab.x * wy + gi * bu.y;
    wx = nx; wy = ny;
  }
  for (; t < t0 + CHUNK; ++t){
    u32 pk = (u32)f2bf(wx) | ((u32)f2bf(wy) << 16);
    *(u32*)(xb + (size_t)t * 1024 + 2 * p) = pk;
    float2 bu = *(const float2*)(bub + (size_t)t * 512 + 2 * p);
    float nx = ab.x * wx - ab.y * wy + gi * bu.x;
    float ny = ab.y * wx + ab.x * wy + gi * bu.y;
    wx = nx; wy = ny;
  }
}

// ------------------------------------------------------------------ bf16 GEMM
// C[M x N] f32 = A[M x K] bf16 (row-major, lda) * B[N x K]^T bf16 (row-major, ldb)
// 128x128 tile, BK=32, 4 waves each 64x64 (4x4 of 16x16x32 MFMA).
static __device__ __forceinline__ void gload16(const u16* g, u16* l){
  __builtin_amdgcn_global_load_lds((const __attribute__((address_space(1))) u32*)g,
                                   (__attribute__((address_space(3))) u32*)l, 16, 0, 0);
}

__global__ __launch_bounds__(256) void gemm_nt(const u16* A, int lda, const u16* B, int ldb,
    float* C, int ldc, int K, int ntn){
  __shared__ u16 As[128 * 32];
  __shared__ u16 Bs[128 * 32];
  int bn = blockIdx.x % ntn, bm = blockIdx.x / ntn;
  int t = threadIdx.x;
  int lane = t & 63, wave = t >> 6;
  const u16* Ag = A + (size_t)(bm * 128 + (t >> 2)) * lda + (t & 3) * 8;
  const u16* Bg = B + (size_t)(bn * 128 + (t >> 2)) * ldb + (t & 3) * 8;
  u16* Asd = As + t * 8;
  u16* Bsd = Bs + t * 8;
  size_t astep = (size_t)64 * lda, bstep = (size_t)64 * ldb;
  f32x4 acc[4][4];
  #pragma unroll
  for (int mi = 0; mi < 4; ++mi)
    #pragma unroll
    for (int ni = 0; ni < 4; ++ni) acc[mi][ni] = (f32x4){0.f, 0.f, 0.f, 0.f};
  int wm = (wave & 1) * 64, wn = (wave >> 1) * 64;
  int fr = lane & 15, kh = (lane >> 4) * 8;
  for (int kt = 0; kt < K; kt += 32){
    __syncthreads();
    gload16(Ag, Asd);
    gload16(Ag + astep, As + 64 * 32 + t * 8);
    gload16(Bg, Bsd);
    gload16(Bg + bstep, Bs + 64 * 32 + t * 8);
    Ag += 32; Bg += 32;
    __syncthreads();
    bf16x8 af[4], bfr[4];
    #pragma unroll
    for (int mi = 0; mi < 4; ++mi)
      af[mi] = *(const bf16x8*)(As + (wm + mi * 16 + fr) * 32 + kh);
    #pragma unroll
    for (int ni = 0; ni < 4; ++ni)
      bfr[ni] = *(const bf16x8*)(Bs + (wn + ni * 16 + fr) * 32 + kh);
    #pragma unroll
    for (int mi = 0; mi < 4; ++mi)
      #pragma unroll
      for (int ni = 0; ni < 4; ++ni)
        acc[mi][ni] = __builtin_amdgcn_mfma_f32_16x16x32_bf16(af[mi], bfr[ni], acc[mi][ni], 0, 0, 0);
  }
  int rq = lane >> 4;
  #pragma unroll
  for (int mi = 0; mi < 4; ++mi)
    #pragma unroll
    for (int ni = 0; ni < 4; ++ni){
      float* cp = C + (size_t)(bm * 128 + wm + mi * 16 + rq * 4) * ldc
                    + (bn * 128 + wn + ni * 16 + fr);
      #pragma unroll
      for (int r = 0; r < 4; ++r) cp[(size_t)r * ldc] = acc[mi][ni][r];
    }
}

// ------------------------------------------------------------------- launcher
extern "C" void kernel_launch(void* const* d_in, const int* in_sizes, int n_in,
                              void* d_out, int out_size, void* d_ws, size_t ws_size,
                              hipStream_t stream){
  const float* u        = (const float*)d_in[0];
  const float* state    = (const float*)d_in[1];
  const float* S        = (const float*)d_in[2];
  const float* rho_raw  = (const float*)d_in[3];
  const float* theta    = (const float*)d_in[4];
  const float* K12      = (const float*)d_in[5];
  const float* K21      = (const float*)d_in[6];
  const float* K22      = (const float*)d_in[7];
  const float* log_gamma= (const float*)d_in[8];

  char* w = (char*)d_ws;
  size_t off = 0;
  auto alloc = [&](size_t bytes)->void*{
    void* p = w + off;
    off = (off + bytes + 255) & ~(size_t)255;
    return p;
  };
  double* alpha = (double*)alloc(64 * 8);
  double* beta2 = (double*)alloc(68 * 8);
  float*  scal  = (float*)alloc(64);
  float2* coef  = (float2*)alloc(256 * 8);
  float*  V[3];
  V[0] = (float*)alloc(1024 * 4);
  V[1] = (float*)alloc(1024 * 4);
  V[2] = (float*)alloc(1024 * 4);
  float*  Y     = (float*)alloc(1024 * 4);
  float*  w0    = (float*)alloc(16 * 512 * 4);
  float*  Kd    = (float*)alloc((size_t)1024 * 1024 * 4);
  float*  KTd   = (float*)alloc((size_t)1024 * 1024 * 4);
  u16*    W12   = (u16*)alloc((size_t)512 * 512 * 2);
  u16*    Wcat  = (u16*)alloc((size_t)512 * 1024 * 2);
  u16*    Xb    = (u16*)alloc((size_t)65536 * 1024 * 2);
  float*  Bu    = (float*)d_out;   // GEMM1 scratch lives in d_out, overwritten by GEMM2

  build_K<<<4096, 256, 0, stream>>>(rho_raw, theta, K12, K21, K22, Kd, KTd);
  init_scalars<<<1, 256, 0, stream>>>(alpha, beta2);
  init_v0<<<4, 256, 0, stream>>>(V[0], beta2);
  for (int j = 0; j < LM; ++j){
    lanczos_av<<<64, 256, 0, stream>>>(Kd, V[j % 3], &beta2[j], Y, &alpha[j]);
    lanczos_atw<<<64, 256, 0, stream>>>(KTd, Y, V[j % 3], &beta2[j],
                                        V[(j + 2) % 3], (j > 0) ? &beta2[j - 1] : &beta2[0],
                                        &alpha[j], V[(j + 1) % 3], &beta2[j + 1], j);
  }
  finalize_sigma<<<1, 256, 0, stream>>>(alpha, beta2, rho_raw, theta, log_gamma, scal, coef);

  conv_u<<<32768, 256, 0, stream>>>((const float4*)u, Xb);
  conv_w12<<<256, 256, 0, stream>>>((const float4*)K12, W12);
  build_wcat<<<2048, 256, 0, stream>>>(K21, K22, scal, Wcat);
  w0_matvec<<<32, 256, 0, stream>>>(S, state, w0);

  // GEMM1: Bu = u_bf16 @ K12^T   (M=65536, N=512, K=512)
  gemm_nt<<<2048, 256, 0, stream>>>(Xb + 512, 1024, W12, 512, Bu, 512, 512, 4);
  // scan: pre (bf16) into X[:, 0:512]
  scan_kernel<<<512, 256, 0, stream>>>(Bu, coef, w0, scal, Xb);
  // GEMM2: y = [pre|u] @ [K21n | gamma*K22n]^T  (M=65536, N=512, K=1024)
  gemm_nt<<<2048, 256, 0, stream>>>(Xb, 1024, Wcat, 1024, (float*)d_out, 512, 1024, 4);
}